// Round 5
// baseline (123.457 us; speedup 1.0000x reference)
//
#include <hip/hip_runtime.h>
#include <hip/hip_bf16.h>

typedef __bf16 bf16;
typedef __bf16 bf16x8 __attribute__((ext_vector_type(8)));
typedef __bf16 bf16x4 __attribute__((ext_vector_type(4)));
typedef float  f32x4  __attribute__((ext_vector_type(4)));

#define MFMA16(a,b,c) __builtin_amdgcn_mfma_f32_16x16x32_bf16((a),(b),(c),0,0,0)

__device__ __forceinline__ void gload_lds16(const void* g, void* l) {
    __builtin_amdgcn_global_load_lds(
        (const __attribute__((address_space(1))) void*)g,
        (__attribute__((address_space(3))) void*)l, 16, 0, 0);
}

// Problem sizes: B=512, T=256, C=512, H=64
// ws layout (bytes):
//   WTfrag [16 KC][12 nf][64 lane][8] bf16 @ 0        (196,608)
//   Qw  [B*T][64] bf16  @ 196608
//   Kw  [B*T][64] bf16  @ 16973824
//   VTw [B][64][256] bf16 @ 33751040

// ---- kernel 0: build pre-fragmented WT --------------------------------------
// WTfrag byte addr (KC*12+nf)*1024 + l*16 holds B-frag: 8 bf16 =
//   W_mat[k = KC*32 + (l>>4)*8 + j][col = (nf&3)*16 + (l&15)],  mat = nf>>2.
__global__ void __launch_bounds__(256) wt_frag_kernel(
        const float* __restrict__ Wq, const float* __restrict__ Wk,
        const float* __restrict__ Wv, bf16* __restrict__ WTfrag) {
    int tid = blockIdx.x * 256 + threadIdx.x;     // 98304 total
    int j  = tid & 7;
    int l  = (tid >> 3) & 63;
    int f  = tid >> 9;            // 0..767 = KC*12 + nf
    int nf = f % 12;
    int KC = f / 12;
    int k   = KC * 32 + (l >> 4) * 8 + j;
    int col = (nf & 3) * 16 + (l & 15);
    const float* W = (nf < 4) ? Wq : ((nf < 8) ? Wk : Wv);
    WTfrag[tid] = (bf16)W[k * 64 + col];
}

// ---- kernel 1: projections (x-only LDS pipeline, 3 blocks/CU) ---------------
// grid 2048, block 256 (4 waves). Block: 64 rows x 192 cols; K-chunks of 64.
// LDS: x[2][64][64] f32 (2x16KB, linear dest, source-XOR-swizzled 16B units).
// B-frags: batched lane-contiguous 1KB register loads from L2-resident WTfrag.
// 3 blocks/CU so one block's barrier drain overlaps the others' stage/compute.
__global__ void __launch_bounds__(256, 3) proj_kernel(
        const float* __restrict__ x, const bf16* __restrict__ WTfrag,
        bf16* __restrict__ Qw, bf16* __restrict__ Kw, bf16* __restrict__ VTw) {
    __shared__ float xt[2][4096];   // [64 rows][64 cols] f32, 16B-unit swizzled

    const int tid = threadIdx.x;
    const int l   = tid & 63;
    const int w   = tid >> 6;
    const int lo  = l & 15;
    const int hi  = l >> 4;
    const int row0 = blockIdx.x * 64;
    const char* xb = (const char*)x;

    // stage x chunk kc (64 f32 cols) -> buffer bx: 1024 16B units, 4 insts/thread.
    // LDS slot s: row = s>>4, physical unit uP = s&15.
    // source logical unit uL = (uP&8) | ((uP&7) ^ (row&7))   [XOR within 128B]
    auto stage_x = [&](int bx, int kc) {
        #pragma unroll
        for (int j = 0; j < 4; ++j) {
            const int s   = j * 256 + tid;
            const int row = s >> 4;
            const int uP  = s & 15;
            const int uL  = (uP & 8) | ((uP & 7) ^ (row & 7));
            const char* src = xb + (size_t)(row0 + row) * 2048 + kc * 256 + uL * 16;
            gload_lds16(src, (char*)xt + bx * 16384 + s * 16);
        }
    };

    f32x4 acc[12];
    #pragma unroll
    for (int nf = 0; nf < 12; ++nf) acc[nf] = (f32x4){0.f, 0.f, 0.f, 0.f};

    stage_x(0, 0);

    #pragma unroll 1
    for (int kc = 0; kc < 8; ++kc) {
        const int cur = kc & 1;
        __syncthreads();                          // drain: xt[cur] ready
        if (kc < 7) stage_x(cur ^ 1, kc + 1);

        #pragma unroll
        for (int KCl = 0; KCl < 2; ++KCl) {
            const int KC = kc * 2 + KCl;          // global K-step 0..15
            // B-frags first (global, L2-resident): 12 batched contiguous loads
            bf16x8 bfr[12];
            #pragma unroll
            for (int nf = 0; nf < 12; ++nf)
                bfr[nf] = *(const bf16x8*)(WTfrag + ((KC * 12 + nf) << 9) + (l << 3));
            // A-frag from swizzled LDS: row w*16+lo, logical units KCl*8+hi*2, +1
            const int rb = (w * 16 + lo) * 256;   // row byte offset
            const int p0 = KCl * 8 + ((hi * 2) ^ (lo & 7));
            const int p1 = KCl * 8 + ((hi * 2 + 1) ^ (lo & 7));
            f32x4 u0 = *(const f32x4*)((char*)xt + cur * 16384 + rb + p0 * 16);
            f32x4 u1 = *(const f32x4*)((char*)xt + cur * 16384 + rb + p1 * 16);
            bf16x8 a;
            a[0] = (bf16)u0[0]; a[1] = (bf16)u0[1]; a[2] = (bf16)u0[2]; a[3] = (bf16)u0[3];
            a[4] = (bf16)u1[0]; a[5] = (bf16)u1[1]; a[6] = (bf16)u1[2]; a[7] = (bf16)u1[3];
            #pragma unroll
            for (int nf = 0; nf < 12; ++nf)
                acc[nf] = MFMA16(a, bfr[nf], acc[nf]);
        }
    }

    // Epilogue. D-frag: n = lo (+nf*16), m = hi*4 + i. Wave owns rows m0..+16.
    const int m0   = row0 + w * 16;
    const int bidx = m0 >> 8;
    const int t0b  = m0 & 255;
    #pragma unroll
    for (int nf = 0; nf < 12; ++nf) {
        const int nn   = nf * 16 + lo;
        const int mrow = m0 + hi * 4;
        if (nf < 4) {
            #pragma unroll
            for (int i = 0; i < 4; ++i)
                Qw[(mrow + i) * 64 + nn] = (bf16)acc[nf][i];
        } else if (nf < 8) {
            #pragma unroll
            for (int i = 0; i < 4; ++i)
                Kw[(mrow + i) * 64 + (nn - 64)] = (bf16)acc[nf][i];
        } else {
            bf16x4 pk;
            pk[0] = (bf16)acc[nf][0]; pk[1] = (bf16)acc[nf][1];
            pk[2] = (bf16)acc[nf][2]; pk[3] = (bf16)acc[nf][3];
            *(bf16x4*)(VTw + ((bidx * 64 + (nn - 128)) * 256 + t0b + hi * 4)) = pk;
        }
    }
}

// ---- kernel 2: causal flash attention (unchanged, passing) ------------------
__global__ void __launch_bounds__(256, 2) attn_kernel(
        const bf16* __restrict__ Qw, const bf16* __restrict__ Kw,
        const bf16* __restrict__ VTw, float* __restrict__ out) {
    __shared__ bf16 Klds[256][72];
    __shared__ bf16 Plds[4][16][72];

    const int tid = threadIdx.x;
    const int l   = tid & 63;
    const int w   = tid >> 6;
    const int lo  = l & 15;
    const int hi  = l >> 4;
    const int b   = blockIdx.x;

    {
        const bf16* src = Kw + b * (256 * 64);
        const int r0 = tid >> 3;
        const int cc = (tid & 7) * 8;
        #pragma unroll
        for (int p = 0; p < 8; ++p) {
            const int row = p * 32 + r0;
            *(bf16x8*)&Klds[row][cc] = *(const bf16x8*)(src + row * 64 + cc);
        }
    }
    __syncthreads();

    bf16x8 qfr[4][2];
    #pragma unroll
    for (int qf = 0; qf < 4; ++qf)
        #pragma unroll
        for (int ks = 0; ks < 2; ++ks)
            qfr[qf][ks] = *(const bf16x8*)(Qw + b * 16384 +
                              (qf * 64 + w * 16 + lo) * 64 + ks * 32 + hi * 8);

    f32x4 o[4][4];
    #pragma unroll
    for (int qf = 0; qf < 4; ++qf)
        #pragma unroll
        for (int mf = 0; mf < 4; ++mf)
            o[qf][mf] = (f32x4){0.f, 0.f, 0.f, 0.f};
    float m2[4]   = {-INFINITY, -INFINITY, -INFINITY, -INFINITY};
    float lsum[4] = {0.f, 0.f, 0.f, 0.f};

    const float SC = 0.125f * 1.44269504088896340736f;

    #pragma unroll
    for (int kc = 0; kc < 4; ++kc) {
        bf16x8 vf[4][2];
        #pragma unroll
        for (int mf = 0; mf < 4; ++mf)
            #pragma unroll
            for (int ks = 0; ks < 2; ++ks)
                vf[mf][ks] = *(const bf16x8*)(VTw + (b * 64 + mf * 16 + lo) * 256 +
                                              kc * 64 + ks * 32 + hi * 8);

        #pragma unroll
        for (int qf = kc; qf < 4; ++qf) {
            f32x4 s[4];
            #pragma unroll
            for (int kf = 0; kf < 4; ++kf) {
                bf16x8 k0 = *(const bf16x8*)&Klds[kc * 64 + kf * 16 + lo][hi * 8];
                bf16x8 k1 = *(const bf16x8*)&Klds[kc * 64 + kf * 16 + lo][32 + hi * 8];
                f32x4 t = (f32x4){0.f, 0.f, 0.f, 0.f};
                t = MFMA16(k0, qfr[qf][0], t);
                t = MFMA16(k1, qfr[qf][1], t);
                s[kf] = t;
            }
            float mx = -INFINITY;
            #pragma unroll
            for (int kf = 0; kf < 4; ++kf)
                #pragma unroll
                for (int i = 0; i < 4; ++i) {
                    float v = s[kf][i] * SC;
                    if (kc == qf && (kf * 16 + hi * 4 + i) > (w * 16 + lo)) v = -INFINITY;
                    s[kf][i] = v;
                    mx = fmaxf(mx, v);
                }
            mx = fmaxf(mx, __shfl_xor(mx, 16));
            mx = fmaxf(mx, __shfl_xor(mx, 32));
            const float mnew = fmaxf(m2[qf], mx);
            const float rsc  = exp2f(m2[qf] - mnew);
            m2[qf] = mnew;

            float cs = 0.f;
            bf16x4 pk[4];
            #pragma unroll
            for (int kf = 0; kf < 4; ++kf)
                #pragma unroll
                for (int i = 0; i < 4; ++i) {
                    float p = exp2f(s[kf][i] - mnew);
                    cs += p;
                    pk[kf][i] = (bf16)p;
                }
            cs += __shfl_xor(cs, 16);
            cs += __shfl_xor(cs, 32);
            lsum[qf] = lsum[qf] * rsc + cs;

            #pragma unroll
            for (int kf = 0; kf < 4; ++kf)
                *(bf16x4*)&Plds[w][lo][kf * 16 + hi * 4] = pk[kf];

            #pragma unroll
            for (int mf = 0; mf < 4; ++mf) {
                o[qf][mf][0] *= rsc; o[qf][mf][1] *= rsc;
                o[qf][mf][2] *= rsc; o[qf][mf][3] *= rsc;
            }
            #pragma unroll
            for (int ks = 0; ks < 2; ++ks) {
                bf16x8 pf = *(const bf16x8*)&Plds[w][lo][ks * 32 + hi * 8];
                #pragma unroll
                for (int mf = 0; mf < 4; ++mf)
                    o[qf][mf] = MFMA16(vf[mf][ks], pf, o[qf][mf]);
            }
        }
    }

    #pragma unroll
    for (int qf = 0; qf < 4; ++qf) {
        const float inv = 1.0f / lsum[qf];
        const int q = qf * 64 + w * 16 + lo;
        #pragma unroll
        for (int mf = 0; mf < 4; ++mf) {
            f32x4 r4;
            r4[0] = o[qf][mf][0] * inv; r4[1] = o[qf][mf][1] * inv;
            r4[2] = o[qf][mf][2] * inv; r4[3] = o[qf][mf][3] * inv;
            *(f32x4*)(out + (b * 256 + q) * 64 + mf * 16 + hi * 4) = r4;
        }
    }
}

// ---- launcher ---------------------------------------------------------------
extern "C" void kernel_launch(void* const* d_in, const int* in_sizes, int n_in,
                              void* d_out, int out_size, void* d_ws, size_t ws_size,
                              hipStream_t stream) {
    const float* x  = (const float*)d_in[0];
    const float* Wq = (const float*)d_in[1];
    const float* Wk = (const float*)d_in[2];
    const float* Wv = (const float*)d_in[3];
    float* out = (float*)d_out;

    char* ws = (char*)d_ws;
    bf16* WTfrag = (bf16*)(ws);
    bf16* Qw  = (bf16*)(ws + 196608);
    bf16* Kw  = (bf16*)(ws + 16973824);
    bf16* VTw = (bf16*)(ws + 33751040);

    wt_frag_kernel<<<dim3(384), dim3(256), 0, stream>>>(Wq, Wk, Wv, WTfrag);
    proj_kernel<<<dim3(2048), dim3(256), 0, stream>>>(x, WTfrag, Qw, Kw, VTw);
    attn_kernel<<<dim3(512), dim3(256), 0, stream>>>(Qw, Kw, VTw, out);
}

// Round 6
// 102.038 us; speedup vs baseline: 1.2099x; 1.2099x over previous
//
#include <hip/hip_runtime.h>
#include <hip/hip_bf16.h>

typedef __bf16 bf16;
typedef __bf16 bf16x8 __attribute__((ext_vector_type(8)));
typedef __bf16 bf16x4 __attribute__((ext_vector_type(4)));
typedef float  f32x4  __attribute__((ext_vector_type(4)));

#define MFMA16(a,b,c) __builtin_amdgcn_mfma_f32_16x16x32_bf16((a),(b),(c),0,0,0)

__device__ __forceinline__ void gld16(const void* g, void* l) {
    __builtin_amdgcn_global_load_lds(
        (const __attribute__((address_space(1))) void*)g,
        (__attribute__((address_space(3))) void*)l, 16, 0, 0);
}

// Problem sizes: B=512, T=256, C=512, H=64
// ws layout (bytes):
//   WTfrag [16 KC][12 nf][64 lane][8] bf16 @ 0        (196,608)
//   Qw  [B*T][64] bf16  @ 196608
//   Kw  [B*T][64] bf16  @ 16973824
//   VTw [B][64][256] bf16 @ 33751040

// ---- kernel 0: build pre-fragmented WT --------------------------------------
__global__ void __launch_bounds__(256) wt_frag_kernel(
        const float* __restrict__ Wq, const float* __restrict__ Wk,
        const float* __restrict__ Wv, bf16* __restrict__ WTfrag) {
    int tid = blockIdx.x * 256 + threadIdx.x;     // 98304 total
    int j  = tid & 7;
    int l  = (tid >> 3) & 63;
    int f  = tid >> 9;            // 0..767 = KC*12 + nf
    int nf = f % 12;
    int KC = f / 12;
    int k   = KC * 32 + (l >> 4) * 8 + j;
    int col = (nf & 3) * 16 + (l & 15);
    const float* W = (nf < 4) ? Wq : ((nf < 8) ? Wk : Wv);
    WTfrag[tid] = (bf16)W[k * 64 + col];
}

// ---- kernel 1: projections — counted-vmcnt 3-deep async pipeline ------------
// grid 2048, block 256 (4 waves). Block: 64 rows x 192 cols; 16 chunks of BK=32.
// LDS 80 KB -> 2 blocks/CU. All in-loop global traffic via global_load_lds;
// steady-state s_waitcnt vmcnt(10) keeps 2 chunks in flight ACROSS barriers.
__global__ void __launch_bounds__(256, 2) proj_kernel(
        const float* __restrict__ x, const bf16* __restrict__ WTfrag,
        bf16* __restrict__ Qw, bf16* __restrict__ Kw, bf16* __restrict__ VTw) {
    __shared__ char smem[81920];   // [0,32768): x[4][64][32]f32 ; rest: B[4][12KB]

    const int tid = threadIdx.x;
    const int l   = tid & 63;
    const int w   = tid >> 6;
    const int lo  = l & 15;
    const int hi  = l >> 4;
    const int row0 = blockIdx.x * 64;
    const char* xb = (const char*)x;
    const char* wb = (const char*)WTfrag;

    auto stage = [&](int buf, int kc) {
        #pragma unroll
        for (int j = 0; j < 2; ++j) {           // x: 512 16B-units, 2/thread
            const int s   = j * 256 + tid;
            const int row = s >> 3;
            const int uP  = s & 7;
            const int uL  = uP ^ (row & 7);     // inverse-swizzle on SOURCE
            gld16(xb + (size_t)(row0 + row) * 2048 + kc * 128 + uL * 16,
                  smem + buf * 8192 + s * 16);
        }
        #pragma unroll
        for (int j = 0; j < 3; ++j) {           // B: 12 KB verbatim, 3/thread
            const int s = j * 256 + tid;
            gld16(wb + kc * 12288 + s * 16,
                  smem + 32768 + buf * 12288 + s * 16);
        }
    };

    f32x4 acc[4][3];
    #pragma unroll
    for (int mf = 0; mf < 4; ++mf)
        #pragma unroll
        for (int j = 0; j < 3; ++j)
            acc[mf][j] = (f32x4){0.f, 0.f, 0.f, 0.f};

    auto compute = [&](int buf) {
        bf16x8 bfr[3];
        #pragma unroll
        for (int j = 0; j < 3; ++j)
            bfr[j] = *(const bf16x8*)(smem + 32768 + buf * 12288 +
                                      (w * 3 + j) * 1024 + l * 16);
        bf16x8 a[4];
        #pragma unroll
        for (int mf = 0; mf < 4; ++mf) {
            const int row = mf * 16 + lo;
            const int u0  = (hi * 2)     ^ (row & 7);
            const int u1  = (hi * 2 + 1) ^ (row & 7);
            f32x4 v0 = *(const f32x4*)(smem + buf * 8192 + row * 128 + u0 * 16);
            f32x4 v1 = *(const f32x4*)(smem + buf * 8192 + row * 128 + u1 * 16);
            bf16x8 t;
            t[0] = (bf16)v0[0]; t[1] = (bf16)v0[1]; t[2] = (bf16)v0[2]; t[3] = (bf16)v0[3];
            t[4] = (bf16)v1[0]; t[5] = (bf16)v1[1]; t[6] = (bf16)v1[2]; t[7] = (bf16)v1[3];
            a[mf] = t;
        }
        #pragma unroll
        for (int mf = 0; mf < 4; ++mf)
            #pragma unroll
            for (int j = 0; j < 3; ++j)
                acc[mf][j] = MFMA16(a[mf], bfr[j], acc[mf][j]);
    };

    stage(0, 0); stage(1, 1); stage(2, 2);      // 15 outstanding / thread

    #pragma unroll 1
    for (int k = 0; k < 13; ++k) {
        asm volatile("s_waitcnt vmcnt(10)" ::: "memory");   // chunk k done
        __builtin_amdgcn_s_barrier();
        __builtin_amdgcn_sched_barrier(0);
        stage((k + 3) & 3, k + 3);   // buf last read in iter k-1: barrier-safe
        compute(k & 3);
    }
    asm volatile("s_waitcnt vmcnt(10)" ::: "memory");
    __builtin_amdgcn_s_barrier();
    __builtin_amdgcn_sched_barrier(0);
    compute(1);                                 // chunk 13
    asm volatile("s_waitcnt vmcnt(5)" ::: "memory");
    __builtin_amdgcn_s_barrier();
    __builtin_amdgcn_sched_barrier(0);
    compute(2);                                 // chunk 14
    asm volatile("s_waitcnt vmcnt(0)" ::: "memory");
    __builtin_amdgcn_s_barrier();
    __builtin_amdgcn_sched_barrier(0);
    compute(3);                                 // chunk 15

    // Epilogue. D-frag: n = lo (+nf*16), m = hi*4 + i (+mf*16).
    const int bidx = row0 >> 8;
    const int t0b  = row0 & 255;
    #pragma unroll
    for (int j = 0; j < 3; ++j) {
        const int nf = w * 3 + j;
        const int nn = nf * 16 + lo;
        #pragma unroll
        for (int mf = 0; mf < 4; ++mf) {
            const int mrow = row0 + mf * 16 + hi * 4;
            if (nf < 4) {
                #pragma unroll
                for (int i = 0; i < 4; ++i)
                    Qw[(mrow + i) * 64 + nn] = (bf16)acc[mf][j][i];
            } else if (nf < 8) {
                #pragma unroll
                for (int i = 0; i < 4; ++i)
                    Kw[(mrow + i) * 64 + (nn - 64)] = (bf16)acc[mf][j][i];
            } else {
                bf16x4 pk;
                pk[0] = (bf16)acc[mf][j][0]; pk[1] = (bf16)acc[mf][j][1];
                pk[2] = (bf16)acc[mf][j][2]; pk[3] = (bf16)acc[mf][j][3];
                const int t0 = t0b + mf * 16 + hi * 4;
                *(bf16x4*)(VTw + ((bidx * 64 + (nn - 128)) * 256 + t0)) = pk;
            }
        }
    }
}

// ---- kernel 2: causal flash attention (unchanged, passing) ------------------
__global__ void __launch_bounds__(256, 2) attn_kernel(
        const bf16* __restrict__ Qw, const bf16* __restrict__ Kw,
        const bf16* __restrict__ VTw, float* __restrict__ out) {
    __shared__ bf16 Klds[256][72];
    __shared__ bf16 Plds[4][16][72];

    const int tid = threadIdx.x;
    const int l   = tid & 63;
    const int w   = tid >> 6;
    const int lo  = l & 15;
    const int hi  = l >> 4;
    const int b   = blockIdx.x;

    {
        const bf16* src = Kw + b * (256 * 64);
        const int r0 = tid >> 3;
        const int cc = (tid & 7) * 8;
        #pragma unroll
        for (int p = 0; p < 8; ++p) {
            const int row = p * 32 + r0;
            *(bf16x8*)&Klds[row][cc] = *(const bf16x8*)(src + row * 64 + cc);
        }
    }
    __syncthreads();

    bf16x8 qfr[4][2];
    #pragma unroll
    for (int qf = 0; qf < 4; ++qf)
        #pragma unroll
        for (int ks = 0; ks < 2; ++ks)
            qfr[qf][ks] = *(const bf16x8*)(Qw + b * 16384 +
                              (qf * 64 + w * 16 + lo) * 64 + ks * 32 + hi * 8);

    f32x4 o[4][4];
    #pragma unroll
    for (int qf = 0; qf < 4; ++qf)
        #pragma unroll
        for (int mf = 0; mf < 4; ++mf)
            o[qf][mf] = (f32x4){0.f, 0.f, 0.f, 0.f};
    float m2[4]   = {-INFINITY, -INFINITY, -INFINITY, -INFINITY};
    float lsum[4] = {0.f, 0.f, 0.f, 0.f};

    const float SC = 0.125f * 1.44269504088896340736f;

    #pragma unroll
    for (int kc = 0; kc < 4; ++kc) {
        bf16x8 vf[4][2];
        #pragma unroll
        for (int mf = 0; mf < 4; ++mf)
            #pragma unroll
            for (int ks = 0; ks < 2; ++ks)
                vf[mf][ks] = *(const bf16x8*)(VTw + (b * 64 + mf * 16 + lo) * 256 +
                                              kc * 64 + ks * 32 + hi * 8);

        #pragma unroll
        for (int qf = kc; qf < 4; ++qf) {
            f32x4 s[4];
            #pragma unroll
            for (int kf = 0; kf < 4; ++kf) {
                bf16x8 k0 = *(const bf16x8*)&Klds[kc * 64 + kf * 16 + lo][hi * 8];
                bf16x8 k1 = *(const bf16x8*)&Klds[kc * 64 + kf * 16 + lo][32 + hi * 8];
                f32x4 t = (f32x4){0.f, 0.f, 0.f, 0.f};
                t = MFMA16(k0, qfr[qf][0], t);
                t = MFMA16(k1, qfr[qf][1], t);
                s[kf] = t;
            }
            float mx = -INFINITY;
            #pragma unroll
            for (int kf = 0; kf < 4; ++kf)
                #pragma unroll
                for (int i = 0; i < 4; ++i) {
                    float v = s[kf][i] * SC;
                    if (kc == qf && (kf * 16 + hi * 4 + i) > (w * 16 + lo)) v = -INFINITY;
                    s[kf][i] = v;
                    mx = fmaxf(mx, v);
                }
            mx = fmaxf(mx, __shfl_xor(mx, 16));
            mx = fmaxf(mx, __shfl_xor(mx, 32));
            const float mnew = fmaxf(m2[qf], mx);
            const float rsc  = exp2f(m2[qf] - mnew);
            m2[qf] = mnew;

            float cs = 0.f;
            bf16x4 pk[4];
            #pragma unroll
            for (int kf = 0; kf < 4; ++kf)
                #pragma unroll
                for (int i = 0; i < 4; ++i) {
                    float p = exp2f(s[kf][i] - mnew);
                    cs += p;
                    pk[kf][i] = (bf16)p;
                }
            cs += __shfl_xor(cs, 16);
            cs += __shfl_xor(cs, 32);
            lsum[qf] = lsum[qf] * rsc + cs;

            #pragma unroll
            for (int kf = 0; kf < 4; ++kf)
                *(bf16x4*)&Plds[w][lo][kf * 16 + hi * 4] = pk[kf];

            #pragma unroll
            for (int mf = 0; mf < 4; ++mf) {
                o[qf][mf][0] *= rsc; o[qf][mf][1] *= rsc;
                o[qf][mf][2] *= rsc; o[qf][mf][3] *= rsc;
            }
            #pragma unroll
            for (int ks = 0; ks < 2; ++ks) {
                bf16x8 pf = *(const bf16x8*)&Plds[w][lo][ks * 32 + hi * 8];
                #pragma unroll
                for (int mf = 0; mf < 4; ++mf)
                    o[qf][mf] = MFMA16(vf[mf][ks], pf, o[qf][mf]);
            }
        }
    }

    #pragma unroll
    for (int qf = 0; qf < 4; ++qf) {
        const float inv = 1.0f / lsum[qf];
        const int q = qf * 64 + w * 16 + lo;
        #pragma unroll
        for (int mf = 0; mf < 4; ++mf) {
            f32x4 r4;
            r4[0] = o[qf][mf][0] * inv; r4[1] = o[qf][mf][1] * inv;
            r4[2] = o[qf][mf][2] * inv; r4[3] = o[qf][mf][3] * inv;
            *(f32x4*)(out + (b * 256 + q) * 64 + mf * 16 + hi * 4) = r4;
        }
    }
}

// ---- launcher ---------------------------------------------------------------
extern "C" void kernel_launch(void* const* d_in, const int* in_sizes, int n_in,
                              void* d_out, int out_size, void* d_ws, size_t ws_size,
                              hipStream_t stream) {
    const float* x  = (const float*)d_in[0];
    const float* Wq = (const float*)d_in[1];
    const float* Wk = (const float*)d_in[2];
    const float* Wv = (const float*)d_in[3];
    float* out = (float*)d_out;

    char* ws = (char*)d_ws;
    bf16* WTfrag = (bf16*)(ws);
    bf16* Qw  = (bf16*)(ws + 196608);
    bf16* Kw  = (bf16*)(ws + 16973824);
    bf16* VTw = (bf16*)(ws + 33751040);

    wt_frag_kernel<<<dim3(384), dim3(256), 0, stream>>>(Wq, Wk, Wv, WTfrag);
    proj_kernel<<<dim3(2048), dim3(256), 0, stream>>>(x, WTfrag, Qw, Kw, VTw);
    attn_kernel<<<dim3(512), dim3(256), 0, stream>>>(Qw, Kw, VTw, out);
}

// Round 7
// 82.689 us; speedup vs baseline: 1.4930x; 1.2340x over previous
//
#include <hip/hip_runtime.h>
#include <hip/hip_bf16.h>

typedef __bf16 bf16;
typedef __bf16 bf16x8 __attribute__((ext_vector_type(8)));
typedef __bf16 bf16x4 __attribute__((ext_vector_type(4)));
typedef float  f32x4  __attribute__((ext_vector_type(4)));

#define MFMA16(a,b,c) __builtin_amdgcn_mfma_f32_16x16x32_bf16((a),(b),(c),0,0,0)

__device__ __forceinline__ void gld16(const void* g, void* l) {
    __builtin_amdgcn_global_load_lds(
        (const __attribute__((address_space(1))) void*)g,
        (__attribute__((address_space(3))) void*)l, 16, 0, 0);
}

// Problem sizes: B=512, T=256, C=512, H=64
// ws layout: WTfrag [16 KC][12 nf][64 lane][8] bf16 @ 0  (196,608 bytes)

// ---- kernel 0: build pre-fragmented WT --------------------------------------
// WTfrag byte addr (KC*12+nf)*1024 + l*16 holds B-frag: 8 bf16 =
//   W_mat[k = KC*32 + (l>>4)*8 + j][col = (nf&3)*16 + (l&15)],  mat = nf>>2.
__global__ void __launch_bounds__(256) wt_frag_kernel(
        const float* __restrict__ Wq, const float* __restrict__ Wk,
        const float* __restrict__ Wv, bf16* __restrict__ WTfrag) {
    int tid = blockIdx.x * 256 + threadIdx.x;     // 98304 total
    int j  = tid & 7;
    int l  = (tid >> 3) & 63;
    int f  = tid >> 9;            // 0..767 = KC*12 + nf
    int nf = f % 12;
    int KC = f / 12;
    int k   = KC * 32 + (l >> 4) * 8 + j;
    int col = (nf & 3) * 16 + (l & 15);
    const float* W = (nf < 4) ? Wq : ((nf < 8) ? Wk : Wv);
    WTfrag[tid] = (bf16)W[k * 64 + col];
}

// ---- fused kernel: proj (streamed, counted-vmcnt) + flash attention ---------
// grid 512 (block = batch), 256 threads (4 waves), 1 block/CU (105 KB LDS).
// Phase 1: stream x[b] in 16 chunks of [256][32] f32; QKV acc in registers
//          (wave w owns rows w*64..+64; lane frag (row=hi*4+i, col=lo)).
// Phase 2: acc -> LDS, unit-XOR-swizzled (Q[256][64], K[256][64], VT[64][256]).
// Phase 3: causal flash attention from LDS; out written straight to HBM.
// LDS map: phase1: xbuf[2]@0/32768 (32KB), wtbuf[2]@65536/77824 (12KB)
//          phase3: Q@0, K@32768, VT@65536, P@98304(9216). total 107520.
__global__ void __launch_bounds__(256, 1) fused_kernel(
        const float* __restrict__ x, const bf16* __restrict__ WTfrag,
        float* __restrict__ out) {
    extern __shared__ char smem[];

    const int tid = threadIdx.x;
    const int l   = tid & 63;
    const int w   = tid >> 6;
    const int lo  = l & 15;
    const int hi  = l >> 4;
    const int b   = blockIdx.x;
    const char* xb = (const char*)x + (size_t)b * 524288;   // 256 rows * 2048 B
    const char* wb = (const char*)WTfrag;

    // ---------------- phase 1: projection ----------------
    auto stage = [&](int buf, int kc) {
        #pragma unroll
        for (int j = 0; j < 8; ++j) {        // x: 2048 16B-units, 8/thread
            const int s   = j * 256 + tid;
            const int row = s >> 3;
            const int uP  = s & 7;
            const int uL  = uP ^ (row & 7);  // inverse-swizzle on SOURCE
            gld16(xb + (size_t)row * 2048 + kc * 128 + uL * 16,
                  smem + buf * 32768 + s * 16);
        }
        #pragma unroll
        for (int j = 0; j < 3; ++j) {        // WT: 12 KB verbatim, 3/thread
            const int s = j * 256 + tid;
            gld16(wb + kc * 12288 + s * 16,
                  smem + 65536 + buf * 12288 + s * 16);
        }
    };

    f32x4 acc[4][12];                        // [mq][nf]; 192 VGPR
    #pragma unroll
    for (int mq = 0; mq < 4; ++mq)
        #pragma unroll
        for (int nf = 0; nf < 12; ++nf)
            acc[mq][nf] = (f32x4){0.f, 0.f, 0.f, 0.f};

    auto compute = [&](int buf) {
        bf16x8 a[4];
        #pragma unroll
        for (int mq = 0; mq < 4; ++mq) {
            const int row = w * 64 + mq * 16 + lo;      // row&7 == lo&7
            const int u0  = (hi * 2)     ^ (lo & 7);
            const int u1  = (hi * 2 + 1) ^ (lo & 7);
            f32x4 v0 = *(const f32x4*)(smem + buf * 32768 + row * 128 + u0 * 16);
            f32x4 v1 = *(const f32x4*)(smem + buf * 32768 + row * 128 + u1 * 16);
            bf16x8 t;
            t[0] = (bf16)v0[0]; t[1] = (bf16)v0[1]; t[2] = (bf16)v0[2]; t[3] = (bf16)v0[3];
            t[4] = (bf16)v1[0]; t[5] = (bf16)v1[1]; t[6] = (bf16)v1[2]; t[7] = (bf16)v1[3];
            a[mq] = t;
        }
        #pragma unroll
        for (int nf = 0; nf < 12; ++nf) {
            bf16x8 bf_ = *(const bf16x8*)(smem + 65536 + buf * 12288 +
                                          nf * 1024 + l * 16);
            #pragma unroll
            for (int mq = 0; mq < 4; ++mq)
                acc[mq][nf] = MFMA16(a[mq], bf_, acc[mq][nf]);
        }
    };

    stage(0, 0);                             // 11 outstanding / thread

    #pragma unroll 1
    for (int k = 0; k < 16; ++k) {
        __builtin_amdgcn_s_barrier();        // buf (k+1)&1 free (reader done)
        if (k + 1 < 16) {
            stage((k + 1) & 1, k + 1);       // now {k:11, k+1:11} outstanding
            asm volatile("s_waitcnt vmcnt(11)" ::: "memory");   // chunk k done
        } else {
            asm volatile("s_waitcnt vmcnt(0)" ::: "memory");
        }
        __builtin_amdgcn_s_barrier();
        __builtin_amdgcn_sched_barrier(0);
        compute(k & 1);
    }

    // ---------------- phase 2: QKV acc -> swizzled LDS ----------------
    __syncthreads();
    {
        char* Qb = smem;
        char* Kb = smem + 32768;
        char* Vb = smem + 65536;
        #pragma unroll
        for (int nf = 0; nf < 12; ++nf) {
            #pragma unroll
            for (int mq = 0; mq < 4; ++mq) {
                #pragma unroll
                for (int i = 0; i < 4; ++i) {
                    bf16 v = (bf16)acc[mq][nf][i];
                    if (nf < 8) {
                        const int row = w * 64 + mq * 16 + hi * 4 + i;
                        const int col = (nf & 3) * 16 + lo;
                        const int u   = col >> 3;
                        char* base = (nf < 4) ? Qb : Kb;
                        *(bf16*)(base + row * 128 + ((u ^ (row & 7)) << 4) +
                                 (col & 7) * 2) = v;
                    } else {
                        const int h = (nf - 8) * 16 + lo;
                        const int t = w * 64 + mq * 16 + hi * 4 + i;
                        const int u = t >> 3;
                        *(bf16*)(Vb + h * 512 + ((u ^ (h & 7)) << 4) +
                                 (t & 7) * 2) = v;
                    }
                }
            }
        }
    }
    __syncthreads();

    // ---------------- phase 3: causal flash attention ----------------
    const char* Qb = smem;
    const char* Kb = smem + 32768;
    const char* Vb = smem + 65536;
    bf16* Pl = (bf16*)(smem + 98304) + w * (16 * 72);   // per-wave [16][72]

    // Q B-frags: q = qf*64 + w*16 + lo (interleaved -> balanced causal work)
    bf16x8 qfr[4][2];
    #pragma unroll
    for (int qf = 0; qf < 4; ++qf)
        #pragma unroll
        for (int ks = 0; ks < 2; ++ks) {
            const int q = qf * 64 + w * 16 + lo;        // q&7 == lo&7
            const int u = ks * 4 + hi;
            qfr[qf][ks] = *(const bf16x8*)(Qb + q * 128 + ((u ^ (lo & 7)) << 4));
        }

    f32x4 o[4][4];
    #pragma unroll
    for (int qf = 0; qf < 4; ++qf)
        #pragma unroll
        for (int mf = 0; mf < 4; ++mf)
            o[qf][mf] = (f32x4){0.f, 0.f, 0.f, 0.f};
    float m2[4]   = {-INFINITY, -INFINITY, -INFINITY, -INFINITY};
    float lsum[4] = {0.f, 0.f, 0.f, 0.f};

    const float SC = 0.125f * 1.44269504088896340736f;  // scale * log2(e)

    #pragma unroll
    for (int kc = 0; kc < 4; ++kc) {
        bf16x8 vf[4][2];
        #pragma unroll
        for (int mf = 0; mf < 4; ++mf)
            #pragma unroll
            for (int ks = 0; ks < 2; ++ks) {
                const int h = mf * 16 + lo;             // h&7 == lo&7
                const int u = kc * 8 + ks * 4 + hi;
                vf[mf][ks] = *(const bf16x8*)(Vb + h * 512 + ((u ^ (lo & 7)) << 4));
            }

        #pragma unroll
        for (int qf = kc; qf < 4; ++qf) {
            f32x4 s[4];
            #pragma unroll
            for (int kf = 0; kf < 4; ++kf) {
                const int key = kc * 64 + kf * 16 + lo; // key&7 == lo&7
                bf16x8 k0 = *(const bf16x8*)(Kb + key * 128 + ((hi ^ (lo & 7)) << 4));
                bf16x8 k1 = *(const bf16x8*)(Kb + key * 128 + (((4 + hi) ^ (lo & 7)) << 4));
                f32x4 t = (f32x4){0.f, 0.f, 0.f, 0.f};
                t = MFMA16(k0, qfr[qf][0], t);
                t = MFMA16(k1, qfr[qf][1], t);
                s[kf] = t;
            }
            float mx = -INFINITY;
            #pragma unroll
            for (int kf = 0; kf < 4; ++kf)
                #pragma unroll
                for (int i = 0; i < 4; ++i) {
                    float v = s[kf][i] * SC;
                    if (kc == qf && (kf * 16 + hi * 4 + i) > (w * 16 + lo)) v = -INFINITY;
                    s[kf][i] = v;
                    mx = fmaxf(mx, v);
                }
            mx = fmaxf(mx, __shfl_xor(mx, 16));
            mx = fmaxf(mx, __shfl_xor(mx, 32));
            const float mnew = fmaxf(m2[qf], mx);
            const float rsc  = exp2f(m2[qf] - mnew);
            m2[qf] = mnew;

            float cs = 0.f;
            bf16x4 pk[4];
            #pragma unroll
            for (int kf = 0; kf < 4; ++kf)
                #pragma unroll
                for (int i = 0; i < 4; ++i) {
                    float p = exp2f(s[kf][i] - mnew);
                    cs += p;
                    pk[kf][i] = (bf16)p;
                }
            cs += __shfl_xor(cs, 16);
            cs += __shfl_xor(cs, 32);
            lsum[qf] = lsum[qf] * rsc + cs;

            #pragma unroll
            for (int kf = 0; kf < 4; ++kf)
                *(bf16x4*)(Pl + lo * 72 + kf * 16 + hi * 4) = pk[kf];

            #pragma unroll
            for (int mf = 0; mf < 4; ++mf) {
                o[qf][mf][0] *= rsc; o[qf][mf][1] *= rsc;
                o[qf][mf][2] *= rsc; o[qf][mf][3] *= rsc;
            }
            #pragma unroll
            for (int ks = 0; ks < 2; ++ks) {
                bf16x8 pf = *(const bf16x8*)(Pl + lo * 72 + ks * 32 + hi * 8);
                #pragma unroll
                for (int mf = 0; mf < 4; ++mf)
                    o[qf][mf] = MFMA16(vf[mf][ks], pf, o[qf][mf]);
            }
        }
    }

    // epilogue: out[b][q][h] fp32, coalesced f32x4
    #pragma unroll
    for (int qf = 0; qf < 4; ++qf) {
        const float inv = 1.0f / lsum[qf];
        const int q = qf * 64 + w * 16 + lo;
        #pragma unroll
        for (int mf = 0; mf < 4; ++mf) {
            f32x4 r4;
            r4[0] = o[qf][mf][0] * inv; r4[1] = o[qf][mf][1] * inv;
            r4[2] = o[qf][mf][2] * inv; r4[3] = o[qf][mf][3] * inv;
            *(f32x4*)(out + (b * 256 + q) * 64 + mf * 16 + hi * 4) = r4;
        }
    }
}

// ---- launcher ---------------------------------------------------------------
extern "C" void kernel_launch(void* const* d_in, const int* in_sizes, int n_in,
                              void* d_out, int out_size, void* d_ws, size_t ws_size,
                              hipStream_t stream) {
    const float* x  = (const float*)d_in[0];
    const float* Wq = (const float*)d_in[1];
    const float* Wk = (const float*)d_in[2];
    const float* Wv = (const float*)d_in[3];
    float* out = (float*)d_out;

    bf16* WTfrag = (bf16*)d_ws;

    wt_frag_kernel<<<dim3(384), dim3(256), 0, stream>>>(Wq, Wk, Wv, WTfrag);
    fused_kernel<<<dim3(512), dim3(256), 107520, stream>>>(x, WTfrag, out);
}

// Round 9
// 71.807 us; speedup vs baseline: 1.7193x; 1.1515x over previous
//
#include <hip/hip_runtime.h>
#include <hip/hip_bf16.h>

typedef __bf16 bf16;
typedef __bf16 bf16x8 __attribute__((ext_vector_type(8)));
typedef __bf16 bf16x4 __attribute__((ext_vector_type(4)));
typedef float  f32x4  __attribute__((ext_vector_type(4)));

#define MFMA16(a,b,c) __builtin_amdgcn_mfma_f32_16x16x32_bf16((a),(b),(c),0,0,0)

__device__ __forceinline__ void gld16(const void* g, void* l) {
    __builtin_amdgcn_global_load_lds(
        (const __attribute__((address_space(1))) void*)g,
        (__attribute__((address_space(3))) void*)l, 16, 0, 0);
}

// Problem sizes: B=512, T=256, C=512, H=64
// ws layout: WTfrag [16 KC][12 nf][64 lane][8] bf16 @ 0  (196,608 bytes)

// ---- kernel 0: build pre-fragmented WT --------------------------------------
// WTfrag byte addr (KC*12+nf)*1024 + l*16 holds B-frag: 8 bf16 =
//   W_mat[k = KC*32 + (l>>4)*8 + j][col = (nf&3)*16 + (l&15)],  mat = nf>>2.
__global__ void __launch_bounds__(256) wt_frag_kernel(
        const float* __restrict__ Wq, const float* __restrict__ Wk,
        const float* __restrict__ Wv, bf16* __restrict__ WTfrag) {
    int tid = blockIdx.x * 256 + threadIdx.x;     // 98304 total
    int j  = tid & 7;
    int l  = (tid >> 3) & 63;
    int f  = tid >> 9;            // 0..767 = KC*12 + nf
    int nf = f % 12;
    int KC = f / 12;
    int k   = KC * 32 + (l >> 4) * 8 + j;
    int col = (nf & 3) * 16 + (l & 15);
    const float* W = (nf < 4) ? Wq : ((nf < 8) ? Wk : Wv);
    WTfrag[tid] = (bf16)W[k * 64 + col];
}

// ---- fused kernel: proj + flash attention (syncthreads-only, 2 blocks/CU) ---
// grid 512 (block = batch), 256 threads (4 waves), LDS 74752 B -> 2 blocks/CU.
// Phase 1: 16 KC chunks; x single buf @0 (32KB, src-XOR-swizzled 16B units),
//          WT single buf @32768 (12KB). ALL sync via __syncthreads() (drains
//          vmcnt(0) -> correct even if the compiler spills; co-resident block
//          covers the drain stalls). Wave w owns rows {mq*64 + w*16 + 0..15}.
// Phase 2: K,V acc -> swizzled LDS (K@0 [256][128B], VT@32768 [64][512B]);
//          Q transposed wave-locally via Pl @65536+w*2304 into registers.
// Phase 3: causal flash attention from LDS; out straight to HBM.
__global__ void __launch_bounds__(256, 2) fused_kernel(
        const float* __restrict__ x, const bf16* __restrict__ WTfrag,
        float* __restrict__ out) {
    extern __shared__ char smem[];

    const int tid = threadIdx.x;
    const int l   = tid & 63;
    const int w   = tid >> 6;
    const int lo  = l & 15;
    const int hi  = l >> 4;
    const int b   = blockIdx.x;
    const char* xb = (const char*)x + (size_t)b * 524288;   // 256 rows * 2048 B
    const char* wb = (const char*)WTfrag;

    // ---------------- phase 1: projection ----------------
    f32x4 acc[4][12];                        // [mq][nf]; 192 VGPR
    #pragma unroll
    for (int mq = 0; mq < 4; ++mq)
        #pragma unroll
        for (int nf = 0; nf < 12; ++nf)
            acc[mq][nf] = (f32x4){0.f, 0.f, 0.f, 0.f};

    #pragma unroll 1
    for (int kc = 0; kc < 16; ++kc) {
        // stage x chunk kc: 2048 16B-units, 8/thread (src-XOR-swizzled)
        #pragma unroll
        for (int j = 0; j < 8; ++j) {
            const int s   = j * 256 + tid;
            const int row = s >> 3;
            const int uP  = s & 7;
            const int uL  = uP ^ (row & 7);  // inverse-swizzle on SOURCE
            gld16(xb + (size_t)row * 2048 + kc * 128 + uL * 16,
                  smem + s * 16);
        }
        // stage WT chunk kc: 12 KB verbatim, 3/thread
        #pragma unroll
        for (int j = 0; j < 3; ++j) {
            const int s = j * 256 + tid;
            gld16(wb + kc * 12288 + s * 16, smem + 32768 + s * 16);
        }
        __syncthreads();                     // vmcnt(0) drain: chunk kc landed

        bf16x8 a[4];
        #pragma unroll
        for (int mq = 0; mq < 4; ++mq) {
            const int row = mq * 64 + w * 16 + lo;      // row&7 == lo&7
            const int u0  = (hi * 2)     ^ (lo & 7);
            const int u1  = (hi * 2 + 1) ^ (lo & 7);
            f32x4 v0 = *(const f32x4*)(smem + row * 128 + u0 * 16);
            f32x4 v1 = *(const f32x4*)(smem + row * 128 + u1 * 16);
            bf16x8 t;
            t[0] = (bf16)v0[0]; t[1] = (bf16)v0[1]; t[2] = (bf16)v0[2]; t[3] = (bf16)v0[3];
            t[4] = (bf16)v1[0]; t[5] = (bf16)v1[1]; t[6] = (bf16)v1[2]; t[7] = (bf16)v1[3];
            a[mq] = t;
        }
        #pragma unroll
        for (int nf = 0; nf < 12; ++nf) {
            bf16x8 bf_ = *(const bf16x8*)(smem + 32768 + nf * 1024 + l * 16);
            #pragma unroll
            for (int mq = 0; mq < 4; ++mq)
                acc[mq][nf] = MFMA16(a[mq], bf_, acc[mq][nf]);
        }
        __syncthreads();                     // all waves done reading bufs
    }

    // ---------------- phase 2: K,V -> LDS; Q -> regs ----------------
    char* Kb = smem;
    char* Vb = smem + 32768;
    #pragma unroll
    for (int nf = 4; nf < 12; ++nf) {
        #pragma unroll
        for (int mq = 0; mq < 4; ++mq) {
            #pragma unroll
            for (int i = 0; i < 4; ++i) {
                bf16 v = (bf16)acc[mq][nf][i];
                if (nf < 8) {
                    const int row = mq * 64 + w * 16 + hi * 4 + i;
                    const int col = (nf - 4) * 16 + lo;
                    const int u   = col >> 3;
                    *(bf16*)(Kb + row * 128 + ((u ^ (row & 7)) << 4) +
                             (col & 7) * 2) = v;
                } else {
                    const int h = (nf - 8) * 16 + lo;
                    const int t = mq * 64 + w * 16 + hi * 4 + i;
                    const int u = t >> 3;
                    *(bf16*)(Vb + h * 512 + ((u ^ (h & 7)) << 4) +
                             (t & 7) * 2) = v;
                }
            }
        }
    }

    // Q: acc[qf][0..3] -> qfr via per-wave LDS transpose ([16][72] @65536+w*2304)
    bf16* Pl = (bf16*)(smem + 65536) + w * 1152;
    bf16x8 qfr[4][2];
    #pragma unroll
    for (int qf = 0; qf < 4; ++qf) {
        #pragma unroll
        for (int nf = 0; nf < 4; ++nf)
            #pragma unroll
            for (int i = 0; i < 4; ++i)
                Pl[(hi * 4 + i) * 72 + nf * 16 + lo] = (bf16)acc[qf][nf][i];
        __syncthreads();                     // writes visible (block-wide, safe)
        #pragma unroll
        for (int ks = 0; ks < 2; ++ks)
            qfr[qf][ks] = *(const bf16x8*)(Pl + lo * 72 + ks * 32 + hi * 8);
        __syncthreads();                     // reads done before next overwrite
    }

    // ---------------- phase 3: causal flash attention ----------------
    f32x4 o[4][4];
    #pragma unroll
    for (int qf = 0; qf < 4; ++qf)
        #pragma unroll
        for (int mf = 0; mf < 4; ++mf)
            o[qf][mf] = (f32x4){0.f, 0.f, 0.f, 0.f};
    float m2[4]   = {-INFINITY, -INFINITY, -INFINITY, -INFINITY};
    float lsum[4] = {0.f, 0.f, 0.f, 0.f};

    const float SC = 0.125f * 1.44269504088896340736f;  // scale * log2(e)

    #pragma unroll
    for (int kc = 0; kc < 4; ++kc) {
        bf16x8 vf[4][2];
        #pragma unroll
        for (int mf = 0; mf < 4; ++mf)
            #pragma unroll
            for (int ks = 0; ks < 2; ++ks) {
                const int h = mf * 16 + lo;             // h&7 == lo&7
                const int u = kc * 8 + ks * 4 + hi;
                vf[mf][ks] = *(const bf16x8*)(Vb + h * 512 + ((u ^ (lo & 7)) << 4));
            }

        #pragma unroll
        for (int qf = kc; qf < 4; ++qf) {
            f32x4 s[4];
            #pragma unroll
            for (int kf = 0; kf < 4; ++kf) {
                const int key = kc * 64 + kf * 16 + lo; // key&7 == lo&7
                bf16x8 k0 = *(const bf16x8*)(Kb + key * 128 + ((hi ^ (lo & 7)) << 4));
                bf16x8 k1 = *(const bf16x8*)(Kb + key * 128 + (((4 + hi) ^ (lo & 7)) << 4));
                f32x4 t = (f32x4){0.f, 0.f, 0.f, 0.f};
                t = MFMA16(k0, qfr[qf][0], t);
                t = MFMA16(k1, qfr[qf][1], t);
                s[kf] = t;
            }
            float mx = -INFINITY;
            #pragma unroll
            for (int kf = 0; kf < 4; ++kf)
                #pragma unroll
                for (int i = 0; i < 4; ++i) {
                    float v = s[kf][i] * SC;
                    if (kc == qf && (kf * 16 + hi * 4 + i) > (w * 16 + lo)) v = -INFINITY;
                    s[kf][i] = v;
                    mx = fmaxf(mx, v);
                }
            mx = fmaxf(mx, __shfl_xor(mx, 16));
            mx = fmaxf(mx, __shfl_xor(mx, 32));
            const float mnew = fmaxf(m2[qf], mx);
            const float rsc  = exp2f(m2[qf] - mnew);
            m2[qf] = mnew;

            float cs = 0.f;
            bf16x4 pk[4];
            #pragma unroll
            for (int kf = 0; kf < 4; ++kf)
                #pragma unroll
                for (int i = 0; i < 4; ++i) {
                    float p = exp2f(s[kf][i] - mnew);
                    cs += p;
                    pk[kf][i] = (bf16)p;
                }
            cs += __shfl_xor(cs, 16);
            cs += __shfl_xor(cs, 32);
            lsum[qf] = lsum[qf] * rsc + cs;

            #pragma unroll
            for (int kf = 0; kf < 4; ++kf)
                *(bf16x4*)(Pl + lo * 72 + kf * 16 + hi * 4) = pk[kf];

            #pragma unroll
            for (int mf = 0; mf < 4; ++mf) {
                o[qf][mf][0] *= rsc; o[qf][mf][1] *= rsc;
                o[qf][mf][2] *= rsc; o[qf][mf][3] *= rsc;
            }
            #pragma unroll
            for (int ks = 0; ks < 2; ++ks) {
                bf16x8 pf = *(const bf16x8*)(Pl + lo * 72 + ks * 32 + hi * 8);
                #pragma unroll
                for (int mf = 0; mf < 4; ++mf)
                    o[qf][mf] = MFMA16(vf[mf][ks], pf, o[qf][mf]);
            }
        }
    }

    // epilogue: out[b][q][h] fp32, coalesced f32x4
    #pragma unroll
    for (int qf = 0; qf < 4; ++qf) {
        const float inv = 1.0f / lsum[qf];
        const int q = qf * 64 + w * 16 + lo;
        #pragma unroll
        for (int mf = 0; mf < 4; ++mf) {
            f32x4 r4;
            r4[0] = o[qf][mf][0] * inv; r4[1] = o[qf][mf][1] * inv;
            r4[2] = o[qf][mf][2] * inv; r4[3] = o[qf][mf][3] * inv;
            *(f32x4*)(out + (b * 256 + q) * 64 + mf * 16 + hi * 4) = r4;
        }
    }
}

// ---- launcher ---------------------------------------------------------------
extern "C" void kernel_launch(void* const* d_in, const int* in_sizes, int n_in,
                              void* d_out, int out_size, void* d_ws, size_t ws_size,
                              hipStream_t stream) {
    const float* x  = (const float*)d_in[0];
    const float* Wq = (const float*)d_in[1];
    const float* Wk = (const float*)d_in[2];
    const float* Wv = (const float*)d_in[3];
    float* out = (float*)d_out;

    bf16* WTfrag = (bf16*)d_ws;

    wt_frag_kernel<<<dim3(384), dim3(256), 0, stream>>>(Wq, Wk, Wv, WTfrag);
    fused_kernel<<<dim3(512), dim3(256), 74752, stream>>>(x, WTfrag, out);
}